// Round 7
// baseline (792.335 us; speedup 1.0000x reference)
//
#include <hip/hip_runtime.h>

#define NN 100000
#define NE 1600000
#define DIN 128
#define HDIM 64
#define DOUT 40
#define EPS 1e-5f
#define NXCD 8

#define SCAN_CHUNK 2048
#define SCAN_NBLK ((NN + SCAN_CHUNK - 1) / SCAN_CHUNK)  // 49

__device__ __forceinline__ float bf2f(unsigned short v) {
    return __uint_as_float(((unsigned int)v) << 16);
}
__device__ __forceinline__ unsigned short f2bf(float f) {
    unsigned int u = __float_as_uint(f);
    u += 0x7FFFu + ((u >> 16) & 1u);   // round-to-nearest-even
    return (unsigned short)(u >> 16);
}

// nontemporal loads ONLY for pure streams with zero reuse (ei scans)
__device__ __forceinline__ int ntl(const int* p) { return __builtin_nontemporal_load(p); }

// ---------------- CSR build ----------------
// XCD-sharded: blocks on XCD p only count dst in p's node range -> cnt lines
// stay in one XCD's L2 (no cross-XCD atomic ping-pong). ei read 8x, nt.
__global__ __launch_bounds__(256) void count_kernel(const int* __restrict__ dst,
                                                    int* __restrict__ cnt) {
    const int xcd = blockIdx.x & (NXCD - 1);
    const int lo = xcd * (NN / NXCD);
    const int hi = (xcd == NXCD - 1) ? NN : lo + (NN / NXCD);
    const int slot = blockIdx.x >> 3;
    const int nslot = gridDim.x >> 3;
    for (int e = slot * blockDim.x + threadIdx.x; e < NE; e += nslot * blockDim.x) {
        int d = ntl(dst + e);
        if (d >= lo && d < hi) atomicAdd(&cnt[d], 1);
    }
}

__global__ __launch_bounds__(256) void dis_kernel(const int* __restrict__ cnt,
                                                  float* __restrict__ dis) {
    for (int i = blockIdx.x * blockDim.x + threadIdx.x; i < NN; i += gridDim.x * blockDim.x)
        dis[i] = rsqrtf((float)(cnt[i] + 1));   // +1 self loop
}

__global__ __launch_bounds__(256) void scan_partial(const int* __restrict__ cnt,
                                                    int* __restrict__ bsum) {
    __shared__ int ls[256];
    const int tid = threadIdx.x;
    int base = blockIdx.x * SCAN_CHUNK + tid * 8;
    int s = 0;
#pragma unroll
    for (int k = 0; k < 8; ++k) {
        int idx = base + k;
        s += (idx < NN) ? cnt[idx] : 0;
    }
    ls[tid] = s;
    __syncthreads();
    for (int off = 128; off > 0; off >>= 1) {
        if (tid < off) ls[tid] += ls[tid + off];
        __syncthreads();
    }
    if (tid == 0) bsum[blockIdx.x] = ls[0];
}

__global__ __launch_bounds__(64) void scan_bsum(int* __restrict__ bsum, int* __restrict__ off) {
    if (threadIdx.x == 0) {
        int run = 0;
        for (int i = 0; i < SCAN_NBLK; ++i) {
            int t = bsum[i];
            bsum[i] = run;
            run += t;
        }
        off[NN] = NE;
    }
}

__global__ __launch_bounds__(256) void scan_scatter(const int* __restrict__ cnt,
                                                    const int* __restrict__ bsum,
                                                    int* __restrict__ off,
                                                    int* __restrict__ cur) {
    __shared__ int part[256];
    const int tid = threadIdx.x;
    const int base = blockIdx.x * SCAN_CHUNK + tid * 8;
    int v[8];
    int s = 0;
#pragma unroll
    for (int k = 0; k < 8; ++k) {
        int idx = base + k;
        v[k] = (idx < NN) ? cnt[idx] : 0;
        s += v[k];
    }
    part[tid] = s;
    __syncthreads();
    if (tid == 0) {
        int run = 0;
        for (int i = 0; i < 256; ++i) {
            int t = part[i];
            part[i] = run;
            run += t;
        }
    }
    __syncthreads();
    int run = bsum[blockIdx.x] + part[tid];
#pragma unroll
    for (int k = 0; k < 8; ++k) {
        int idx = base + k;
        if (idx < NN) { off[idx] = run; cur[idx] = run; }
        run += v[k];
    }
}

// XCD-sharded fill with nontemporal edge reads.
__global__ __launch_bounds__(256) void fill_kernel(const int* __restrict__ ei,
                                                   int* __restrict__ cur,
                                                   int* __restrict__ esrc) {
    const int xcd = blockIdx.x & (NXCD - 1);
    const int lo = xcd * (NN / NXCD);
    const int hi = (xcd == NXCD - 1) ? NN : lo + (NN / NXCD);
    const int slot = blockIdx.x >> 3;
    const int nslot = gridDim.x >> 3;
    for (int e = slot * blockDim.x + threadIdx.x; e < NE; e += nslot * blockDim.x) {
        int d = ntl(ei + NE + e);
        if (d >= lo && d < hi) {
            int pos = atomicAdd(&cur[d], 1);
            esrc[pos] = ntl(ei + e);
        }
    }
}

// ---------------- dense GEMM: h2[N,64] = bf16( (bn?(x)[N,K] @ W[K,64]) * dis[row] )
// x tile staged in LDS via coalesced float4 loads; optional fused BN+ReLU on
// the staged input (sc/sh per channel); W column in VGPRs.
template <int K, int TR, bool BN>
__global__ __launch_bounds__(256) void gemm_lds(const float* __restrict__ x,
                                                const float* __restrict__ W,
                                                const float* __restrict__ dis,
                                                const float* __restrict__ sc,
                                                const float* __restrict__ sh,
                                                unsigned short* __restrict__ h2) {
    __shared__ float xs[TR][K];
    const int tid = threadIdx.x;
    const int lane = tid & 63;
    const int wv = tid >> 6;
    float w[K];
#pragma unroll
    for (int k = 0; k < K; ++k) w[k] = W[k * 64 + lane];

    float4 scv, shv;
    if (BN) {
        const int c4 = tid & (K / 4 - 1);   // column group is constant per thread
        scv = ((const float4*)sc)[c4];
        shv = ((const float4*)sh)[c4];
    }

    const int row0 = blockIdx.x * TR;
    const int remRows = NN - row0;
    const int nvec = ((remRows >= TR) ? TR : remRows) * K / 4;
    const float4* srcv = (const float4*)(x + (long long)row0 * K);
    float4* dstv = (float4*)&xs[0][0];
    for (int i = tid; i < nvec; i += 256) {
        float4 v = srcv[i];
        if (BN) {
            v.x = fmaxf(fmaf(v.x, scv.x, shv.x), 0.f);
            v.y = fmaxf(fmaf(v.y, scv.y, shv.y), 0.f);
            v.z = fmaxf(fmaf(v.z, scv.z, shv.z), 0.f);
            v.w = fmaxf(fmaf(v.w, scv.w, shv.w), 0.f);
        }
        dstv[i] = v;
    }
    __syncthreads();

    const int rpw = TR / 4;
#pragma unroll
    for (int rr = 0; rr < rpw; ++rr) {
        const int r = wv * rpw + rr;
        const int row = row0 + r;
        if (row >= NN) break;
        float a0 = 0.f, a1 = 0.f, a2 = 0.f, a3 = 0.f;
#pragma unroll
        for (int k = 0; k < K; k += 4) {
            float4 xv = *(const float4*)&xs[r][k];
            a0 = fmaf(xv.x, w[k + 0], a0);
            a1 = fmaf(xv.y, w[k + 1], a1);
            a2 = fmaf(xv.z, w[k + 2], a2);
            a3 = fmaf(xv.w, w[k + 3], a3);
        }
        h2[row * 64 + lane] = f2bf(((a0 + a1) + (a2 + a3)) * dis[row]);
    }
}

// ---------------- CSR gather: y[n] = dis[n] * (h2[n] + sum_in h2[src]) ------
// 2 nodes per wave -> two independent load chains (2x MLP). Branches are
// wave-uniform (jb/deg uniform across the wave).
__global__ __launch_bounds__(256) void agg_csr(const int* __restrict__ off,
                                               const int* __restrict__ esrc,
                                               const float* __restrict__ dis,
                                               const unsigned short* __restrict__ h2,
                                               float* __restrict__ y) {
    const int n0 = blockIdx.x * 8 + (threadIdx.x >> 6) * 2;
    const int n1 = n0 + 1;
    const int c = threadIdx.x & 63;
    float acc0 = bf2f(h2[n0 * 64 + c]);
    float acc1 = bf2f(h2[n1 * 64 + c]);
    const int jb0 = off[n0], d0 = off[n0 + 1] - jb0;
    const int jb1 = off[n1], d1 = off[n1 + 1] - jb1;
    const int m = (d0 > d1) ? d0 : d1;
#pragma unroll 4
    for (int t = 0; t < m; ++t) {
        if (t < d0) acc0 += bf2f(h2[esrc[jb0 + t] * 64 + c]);
        if (t < d1) acc1 += bf2f(h2[esrc[jb1 + t] * 64 + c]);
    }
    y[n0 * 64 + c] = acc0 * dis[n0];
    y[n1 * 64 + c] = acc1 * dis[n1];
}

// ---------------- per-channel sum / sumsq ----------------
__global__ __launch_bounds__(256) void stats_kernel(const float* __restrict__ y, float* stats) {
    const int tid = threadIdx.x;
    const int c = tid & 63, rg = tid >> 6;
    float s = 0.f, s2 = 0.f;
    for (int row = blockIdx.x * 4 + rg; row < NN; row += gridDim.x * 4) {
        float v = y[row * 64 + c];
        s += v;
        s2 += v * v;
    }
    __shared__ float ls[256], ls2[256];
    ls[tid] = s; ls2[tid] = s2;
    __syncthreads();
    if (tid < 64) {
        s = ls[tid] + ls[tid + 64] + ls[tid + 128] + ls[tid + 192];
        s2 = ls2[tid] + ls2[tid + 64] + ls2[tid + 128] + ls2[tid + 192];
        atomicAdd(&stats[tid], s);
        atomicAdd(&stats[64 + tid], s2);
    }
}

// ---------------- BN coefficients: sc = g*rsqrt(var+eps), sh = beta-mean*sc --
__global__ __launch_bounds__(64) void bn_coef(const float* __restrict__ stats,
                                              const float* __restrict__ g,
                                              const float* __restrict__ beta,
                                              float* __restrict__ sc,
                                              float* __restrict__ sh) {
    const int c = threadIdx.x;
    const float invN = 1.0f / NN;
    float m = stats[c] * invN;
    float var = stats[64 + c] * invN - m * m;
    float s = g[c] * rsqrtf(var + EPS);
    sc[c] = s;
    sh[c] = beta[c] - m * s;
}

// ---------------- JK max (BN applied on the fly) + final linear -------------
__global__ __launch_bounds__(256) void final_kernel(const float* __restrict__ x1,
                                                    const float* __restrict__ x2,
                                                    const float* __restrict__ x3,
                                                    const float* __restrict__ sc1,
                                                    const float* __restrict__ sh1,
                                                    const float* __restrict__ sc2,
                                                    const float* __restrict__ sh2,
                                                    const float* __restrict__ b3,
                                                    const float* __restrict__ Wf,
                                                    const float* __restrict__ bf,
                                                    float* __restrict__ out) {
    __shared__ float m[4][64];
    const int tid = threadIdx.x;
    const int r = tid >> 6, c = tid & 63;
    const int row = blockIdx.x * 4 + r;
    int o = row * 64 + c;
    float v1 = fmaxf(fmaf(x1[o], sc1[c], sh1[c]), 0.f);
    float v2 = fmaxf(fmaf(x2[o], sc2[c], sh2[c]), 0.f);
    float v3 = x3[o] + b3[c];
    m[r][c] = fmaxf(fmaxf(v1, v2), v3);
    __syncthreads();
    if (c < DOUT) {
        float acc = bf[c];
#pragma unroll
        for (int k = 0; k < 64; ++k) acc += m[r][k] * Wf[k * DOUT + c];
        out[row * DOUT + c] = acc;
    }
}

extern "C" void kernel_launch(void* const* d_in, const int* in_sizes, int n_in,
                              void* d_out, int out_size, void* d_ws, size_t ws_size,
                              hipStream_t stream) {
    const float* node_feat = (const float*)d_in[0];
    const int*   ei        = (const int*)d_in[1];
    const float* W1 = (const float*)d_in[2];
    const float* g1 = (const float*)d_in[4];
    const float* beta1 = (const float*)d_in[5];
    const float* W2 = (const float*)d_in[6];
    const float* g2 = (const float*)d_in[8];
    const float* beta2 = (const float*)d_in[9];
    const float* W3 = (const float*)d_in[10];
    const float* b3 = (const float*)d_in[11];
    const float* Wf = (const float*)d_in[12];
    const float* bf = (const float*)d_in[13];
    float* out = (float*)d_out;

    // workspace layout
    float* ws  = (float*)d_ws;
    float* dis = ws;                                       // N
    unsigned short* h2 = (unsigned short*)(dis + NN);      // N*64 bf16
    float* x1  = (float*)(h2 + NN * 64);                   // N*64 f32
    float* x2  = x1 + NN * 64;
    float* x3  = x2 + NN * 64;
    float* stats = x3 + NN * 64;                           // 128
    float* sc1 = stats + 128;                              // 64
    float* sh1 = sc1 + 64;                                 // 64
    float* sc2 = sh1 + 64;                                 // 64
    float* sh2 = sc2 + 64;                                 // 64
    int* cnt  = (int*)(sh2 + 64);                          // N
    int* cur  = cnt + NN;                                  // N
    int* bsum = cur + NN;                                  // 64
    int* off  = bsum + 64;                                 // N+1
    int* esrc = off + NN + 1;                              // E

    const int B = 256;
    const int gElem = 2048;
    const int gRows = NN / 4;     // 25000
    const int gAgg  = NN / 8;     // 12500 (2 nodes per wave)

    // ---- CSR build + normalization ----
    hipMemsetAsync(cnt, 0, NN * sizeof(int), stream);
    count_kernel<<<gElem, B, 0, stream>>>(ei + NE, cnt);
    dis_kernel<<<512, B, 0, stream>>>(cnt, dis);
    scan_partial<<<SCAN_NBLK, B, 0, stream>>>(cnt, bsum);
    scan_bsum<<<1, 64, 0, stream>>>(bsum, off);
    scan_scatter<<<SCAN_NBLK, B, 0, stream>>>(cnt, bsum, off, cur);
    fill_kernel<<<gElem, B, 0, stream>>>(ei, cur, esrc);

    // ---- layer 1 ----
    gemm_lds<DIN, 32, false><<<(NN + 31) / 32, B, 0, stream>>>(node_feat, W1, dis, nullptr, nullptr, h2);
    agg_csr<<<gAgg, B, 0, stream>>>(off, esrc, dis, h2, x1);
    hipMemsetAsync(stats, 0, 128 * sizeof(float), stream);
    stats_kernel<<<512, B, 0, stream>>>(x1, stats);
    bn_coef<<<1, 64, 0, stream>>>(stats, g1, beta1, sc1, sh1);

    // ---- layer 2 (BN1+ReLU fused into staging) ----
    gemm_lds<HDIM, 64, true><<<(NN + 63) / 64, B, 0, stream>>>(x1, W2, dis, sc1, sh1, h2);
    agg_csr<<<gAgg, B, 0, stream>>>(off, esrc, dis, h2, x2);
    hipMemsetAsync(stats, 0, 128 * sizeof(float), stream);
    stats_kernel<<<512, B, 0, stream>>>(x2, stats);
    bn_coef<<<1, 64, 0, stream>>>(stats, g2, beta2, sc2, sh2);

    // ---- layer 3 (BN2+ReLU fused; b3 folded into final) ----
    gemm_lds<HDIM, 64, true><<<(NN + 63) / 64, B, 0, stream>>>(x2, W3, dis, sc2, sh2, h2);
    agg_csr<<<gAgg, B, 0, stream>>>(off, esrc, dis, h2, x3);

    // ---- JK max (BN on the fly) + final linear ----
    final_kernel<<<gRows, B, 0, stream>>>(x1, x2, x3, sc1, sh1, sc2, sh2, b3, Wf, bf, out);
}

// Round 8
// 498.953 us; speedup vs baseline: 1.5880x; 1.5880x over previous
//
#include <hip/hip_runtime.h>

#define NN 100000
#define NE 1600000
#define DIN 128
#define HDIM 64
#define DOUT 40
#define EPS 1e-5f
#define NXCD 8

#define SCAN_CHUNK 2048
#define SCAN_NBLK ((NN + SCAN_CHUNK - 1) / SCAN_CHUNK)  // 49

__device__ __forceinline__ float bf2f(unsigned short v) {
    return __uint_as_float(((unsigned int)v) << 16);
}
__device__ __forceinline__ unsigned short f2bf(float f) {
    unsigned int u = __float_as_uint(f);
    u += 0x7FFFu + ((u >> 16) & 1u);   // round-to-nearest-even
    return (unsigned short)(u >> 16);
}

// nontemporal loads ONLY for pure streams with zero reuse (ei scans)
__device__ __forceinline__ int ntl(const int* p) { return __builtin_nontemporal_load(p); }

// ---------------- CSR build ----------------
__global__ __launch_bounds__(256) void count_kernel(const int* __restrict__ dst,
                                                    int* __restrict__ cnt) {
    const int xcd = blockIdx.x & (NXCD - 1);
    const int lo = xcd * (NN / NXCD);
    const int hi = (xcd == NXCD - 1) ? NN : lo + (NN / NXCD);
    const int slot = blockIdx.x >> 3;
    const int nslot = gridDim.x >> 3;
    for (int e = slot * blockDim.x + threadIdx.x; e < NE; e += nslot * blockDim.x) {
        int d = ntl(dst + e);
        if (d >= lo && d < hi) atomicAdd(&cnt[d], 1);
    }
}

__global__ __launch_bounds__(256) void dis_kernel(const int* __restrict__ cnt,
                                                  float* __restrict__ dis) {
    for (int i = blockIdx.x * blockDim.x + threadIdx.x; i < NN; i += gridDim.x * blockDim.x)
        dis[i] = rsqrtf((float)(cnt[i] + 1));   // +1 self loop
}

__global__ __launch_bounds__(256) void scan_partial(const int* __restrict__ cnt,
                                                    int* __restrict__ bsum) {
    __shared__ int ls[256];
    const int tid = threadIdx.x;
    int base = blockIdx.x * SCAN_CHUNK + tid * 8;
    int s = 0;
#pragma unroll
    for (int k = 0; k < 8; ++k) {
        int idx = base + k;
        s += (idx < NN) ? cnt[idx] : 0;
    }
    ls[tid] = s;
    __syncthreads();
    for (int off = 128; off > 0; off >>= 1) {
        if (tid < off) ls[tid] += ls[tid + off];
        __syncthreads();
    }
    if (tid == 0) bsum[blockIdx.x] = ls[0];
}

__global__ __launch_bounds__(64) void scan_bsum(int* __restrict__ bsum, int* __restrict__ off) {
    if (threadIdx.x == 0) {
        int run = 0;
        for (int i = 0; i < SCAN_NBLK; ++i) {
            int t = bsum[i];
            bsum[i] = run;
            run += t;
        }
        off[NN] = NE;
    }
}

__global__ __launch_bounds__(256) void scan_scatter(const int* __restrict__ cnt,
                                                    const int* __restrict__ bsum,
                                                    int* __restrict__ off,
                                                    int* __restrict__ cur) {
    __shared__ int part[256];
    const int tid = threadIdx.x;
    const int base = blockIdx.x * SCAN_CHUNK + tid * 8;
    int v[8];
    int s = 0;
#pragma unroll
    for (int k = 0; k < 8; ++k) {
        int idx = base + k;
        v[k] = (idx < NN) ? cnt[idx] : 0;
        s += v[k];
    }
    part[tid] = s;
    __syncthreads();
    if (tid == 0) {
        int run = 0;
        for (int i = 0; i < 256; ++i) {
            int t = part[i];
            part[i] = run;
            run += t;
        }
    }
    __syncthreads();
    int run = bsum[blockIdx.x] + part[tid];
#pragma unroll
    for (int k = 0; k < 8; ++k) {
        int idx = base + k;
        if (idx < NN) { off[idx] = run; cur[idx] = run; }
        run += v[k];
    }
}

// XCD-sharded fill with nontemporal edge reads.
__global__ __launch_bounds__(256) void fill_kernel(const int* __restrict__ ei,
                                                   int* __restrict__ cur,
                                                   int* __restrict__ esrc) {
    const int xcd = blockIdx.x & (NXCD - 1);
    const int lo = xcd * (NN / NXCD);
    const int hi = (xcd == NXCD - 1) ? NN : lo + (NN / NXCD);
    const int slot = blockIdx.x >> 3;
    const int nslot = gridDim.x >> 3;
    for (int e = slot * blockDim.x + threadIdx.x; e < NE; e += nslot * blockDim.x) {
        int d = ntl(ei + NE + e);
        if (d >= lo && d < hi) {
            int pos = atomicAdd(&cur[d], 1);
            esrc[pos] = ntl(ei + e);
        }
    }
}

// ---------------- dense GEMM: h2[N,64] = bf16( (bn?(x)[N,K] @ W[K,64]) * dis[row] )
template <int K, int TR, bool BN>
__global__ __launch_bounds__(256) void gemm_lds(const float* __restrict__ x,
                                                const float* __restrict__ W,
                                                const float* __restrict__ dis,
                                                const float* __restrict__ sc,
                                                const float* __restrict__ sh,
                                                unsigned short* __restrict__ h2) {
    __shared__ float xs[TR][K];
    const int tid = threadIdx.x;
    const int lane = tid & 63;
    const int wv = tid >> 6;
    float w[K];
#pragma unroll
    for (int k = 0; k < K; ++k) w[k] = W[k * 64 + lane];

    float4 scv, shv;
    if (BN) {
        const int c4 = tid & (K / 4 - 1);   // column group is constant per thread
        scv = ((const float4*)sc)[c4];
        shv = ((const float4*)sh)[c4];
    }

    const int row0 = blockIdx.x * TR;
    const int remRows = NN - row0;
    const int nvec = ((remRows >= TR) ? TR : remRows) * K / 4;
    const float4* srcv = (const float4*)(x + (long long)row0 * K);
    float4* dstv = (float4*)&xs[0][0];
    for (int i = tid; i < nvec; i += 256) {
        float4 v = srcv[i];
        if (BN) {
            v.x = fmaxf(fmaf(v.x, scv.x, shv.x), 0.f);
            v.y = fmaxf(fmaf(v.y, scv.y, shv.y), 0.f);
            v.z = fmaxf(fmaf(v.z, scv.z, shv.z), 0.f);
            v.w = fmaxf(fmaf(v.w, scv.w, shv.w), 0.f);
        }
        dstv[i] = v;
    }
    __syncthreads();

    const int rpw = TR / 4;
#pragma unroll
    for (int rr = 0; rr < rpw; ++rr) {
        const int r = wv * rpw + rr;
        const int row = row0 + r;
        if (row >= NN) break;
        float a0 = 0.f, a1 = 0.f, a2 = 0.f, a3 = 0.f;
#pragma unroll
        for (int k = 0; k < K; k += 4) {
            float4 xv = *(const float4*)&xs[r][k];
            a0 = fmaf(xv.x, w[k + 0], a0);
            a1 = fmaf(xv.y, w[k + 1], a1);
            a2 = fmaf(xv.z, w[k + 2], a2);
            a3 = fmaf(xv.w, w[k + 3], a3);
        }
        h2[row * 64 + lane] = f2bf(((a0 + a1) + (a2 + a3)) * dis[row]);
    }
}

// ---------------- CSR gather: y[n] = dis[n] * (h2[n] + sum_in h2[src]) ------
// r5 form: 1 node/wave, plain loads, unroll 8 -> compiler batches 8
// independent index+gather pairs. jb/je scalarized (wave-uniform).
__global__ __launch_bounds__(256) void agg_csr(const int* __restrict__ off,
                                               const int* __restrict__ esrc,
                                               const float* __restrict__ dis,
                                               const unsigned short* __restrict__ h2,
                                               float* __restrict__ y) {
    const int node = blockIdx.x * 4 + (threadIdx.x >> 6);
    const int c = threadIdx.x & 63;
    float acc = bf2f(h2[node * 64 + c]);
    const int jb = __builtin_amdgcn_readfirstlane(off[node]);
    const int je = __builtin_amdgcn_readfirstlane(off[node + 1]);
#pragma unroll 8
    for (int j = jb; j < je; ++j) {
        acc += bf2f(h2[esrc[j] * 64 + c]);
    }
    y[node * 64 + c] = acc * dis[node];
}

// ---------------- layer-3 agg fused with JK max + final linear --------------
__global__ __launch_bounds__(256) void agg_final(const int* __restrict__ off,
                                                 const int* __restrict__ esrc,
                                                 const float* __restrict__ dis,
                                                 const unsigned short* __restrict__ h2,
                                                 const float* __restrict__ x1,
                                                 const float* __restrict__ x2,
                                                 const float* __restrict__ sc1,
                                                 const float* __restrict__ sh1,
                                                 const float* __restrict__ sc2,
                                                 const float* __restrict__ sh2,
                                                 const float* __restrict__ b3,
                                                 const float* __restrict__ Wf,
                                                 const float* __restrict__ bf,
                                                 float* __restrict__ out) {
    __shared__ float m[4][64];
    const int r = threadIdx.x >> 6;
    const int node = blockIdx.x * 4 + r;
    const int c = threadIdx.x & 63;
    float acc = bf2f(h2[node * 64 + c]);
    const int jb = __builtin_amdgcn_readfirstlane(off[node]);
    const int je = __builtin_amdgcn_readfirstlane(off[node + 1]);
#pragma unroll 8
    for (int j = jb; j < je; ++j) {
        acc += bf2f(h2[esrc[j] * 64 + c]);
    }
    const int o = node * 64 + c;
    float v3 = acc * dis[node] + b3[c];
    float v1 = fmaxf(fmaf(x1[o], sc1[c], sh1[c]), 0.f);
    float v2 = fmaxf(fmaf(x2[o], sc2[c], sh2[c]), 0.f);
    m[r][c] = fmaxf(fmaxf(v1, v2), v3);
    __syncthreads();
    if (c < DOUT) {
        float acc2 = bf[c];
#pragma unroll
        for (int k = 0; k < 64; ++k) acc2 += m[r][k] * Wf[k * DOUT + c];
        out[node * DOUT + c] = acc2;
    }
}

// ---------------- per-channel sum / sumsq ----------------
__global__ __launch_bounds__(256) void stats_kernel(const float* __restrict__ y, float* stats) {
    const int tid = threadIdx.x;
    const int c = tid & 63, rg = tid >> 6;
    float s = 0.f, s2 = 0.f;
    for (int row = blockIdx.x * 4 + rg; row < NN; row += gridDim.x * 4) {
        float v = y[row * 64 + c];
        s += v;
        s2 += v * v;
    }
    __shared__ float ls[256], ls2[256];
    ls[tid] = s; ls2[tid] = s2;
    __syncthreads();
    if (tid < 64) {
        s = ls[tid] + ls[tid + 64] + ls[tid + 128] + ls[tid + 192];
        s2 = ls2[tid] + ls2[tid + 64] + ls2[tid + 128] + ls2[tid + 192];
        atomicAdd(&stats[tid], s);
        atomicAdd(&stats[64 + tid], s2);
    }
}

// ---------------- BN coefficients: sc = g*rsqrt(var+eps), sh = beta-mean*sc --
__global__ __launch_bounds__(64) void bn_coef(const float* __restrict__ stats,
                                              const float* __restrict__ g,
                                              const float* __restrict__ beta,
                                              float* __restrict__ sc,
                                              float* __restrict__ sh) {
    const int c = threadIdx.x;
    const float invN = 1.0f / NN;
    float m = stats[c] * invN;
    float var = stats[64 + c] * invN - m * m;
    float s = g[c] * rsqrtf(var + EPS);
    sc[c] = s;
    sh[c] = beta[c] - m * s;
}

extern "C" void kernel_launch(void* const* d_in, const int* in_sizes, int n_in,
                              void* d_out, int out_size, void* d_ws, size_t ws_size,
                              hipStream_t stream) {
    const float* node_feat = (const float*)d_in[0];
    const int*   ei        = (const int*)d_in[1];
    const float* W1 = (const float*)d_in[2];
    const float* g1 = (const float*)d_in[4];
    const float* beta1 = (const float*)d_in[5];
    const float* W2 = (const float*)d_in[6];
    const float* g2 = (const float*)d_in[8];
    const float* beta2 = (const float*)d_in[9];
    const float* W3 = (const float*)d_in[10];
    const float* b3 = (const float*)d_in[11];
    const float* Wf = (const float*)d_in[12];
    const float* bf = (const float*)d_in[13];
    float* out = (float*)d_out;

    // workspace layout
    float* ws  = (float*)d_ws;
    float* dis = ws;                                       // N
    unsigned short* h2 = (unsigned short*)(dis + NN);      // N*64 bf16
    float* x1  = (float*)(h2 + NN * 64);                   // N*64 f32
    float* x2  = x1 + NN * 64;
    float* stats = x2 + NN * 64;                           // 128
    float* sc1 = stats + 128;                              // 64
    float* sh1 = sc1 + 64;                                 // 64
    float* sc2 = sh1 + 64;                                 // 64
    float* sh2 = sc2 + 64;                                 // 64
    int* cnt  = (int*)(sh2 + 64);                          // N
    int* cur  = cnt + NN;                                  // N
    int* bsum = cur + NN;                                  // 64
    int* off  = bsum + 64;                                 // N+1
    int* esrc = off + NN + 1;                              // E

    const int B = 256;
    const int gElem = 2048;
    const int gRows = NN / 4;     // 25000

    // ---- CSR build + normalization ----
    hipMemsetAsync(cnt, 0, NN * sizeof(int), stream);
    count_kernel<<<gElem, B, 0, stream>>>(ei + NE, cnt);
    dis_kernel<<<512, B, 0, stream>>>(cnt, dis);
    scan_partial<<<SCAN_NBLK, B, 0, stream>>>(cnt, bsum);
    scan_bsum<<<1, 64, 0, stream>>>(bsum, off);
    scan_scatter<<<SCAN_NBLK, B, 0, stream>>>(cnt, bsum, off, cur);
    fill_kernel<<<gElem, B, 0, stream>>>(ei, cur, esrc);

    // ---- layer 1 ----
    gemm_lds<DIN, 32, false><<<(NN + 31) / 32, B, 0, stream>>>(node_feat, W1, dis, nullptr, nullptr, h2);
    agg_csr<<<gRows, B, 0, stream>>>(off, esrc, dis, h2, x1);
    hipMemsetAsync(stats, 0, 128 * sizeof(float), stream);
    stats_kernel<<<512, B, 0, stream>>>(x1, stats);
    bn_coef<<<1, 64, 0, stream>>>(stats, g1, beta1, sc1, sh1);

    // ---- layer 2 (BN1+ReLU fused into staging) ----
    gemm_lds<HDIM, 64, true><<<(NN + 63) / 64, B, 0, stream>>>(x1, W2, dis, sc1, sh1, h2);
    agg_csr<<<gRows, B, 0, stream>>>(off, esrc, dis, h2, x2);
    hipMemsetAsync(stats, 0, 128 * sizeof(float), stream);
    stats_kernel<<<512, B, 0, stream>>>(x2, stats);
    bn_coef<<<1, 64, 0, stream>>>(stats, g2, beta2, sc2, sh2);

    // ---- layer 3 (BN2+ReLU fused into staging; agg fused with JK+final) ----
    gemm_lds<HDIM, 64, true><<<(NN + 63) / 64, B, 0, stream>>>(x2, W3, dis, sc2, sh2, h2);
    agg_final<<<gRows, B, 0, stream>>>(off, esrc, dis, h2, x1, x2,
                                       sc1, sh1, sc2, sh2, b3, Wf, bf, out);
}

// Round 9
// 492.385 us; speedup vs baseline: 1.6092x; 1.0133x over previous
//
#include <hip/hip_runtime.h>

#define NN 100000
#define NE 1600000
#define DIN 128
#define HDIM 64
#define DOUT 40
#define EPS 1e-5f
#define NXCD 8

#define SCAN_CHUNK 2048
#define SCAN_NBLK ((NN + SCAN_CHUNK - 1) / SCAN_CHUNK)  // 49

typedef int int4v __attribute__((ext_vector_type(4)));

__device__ __forceinline__ float bf2f(unsigned short v) {
    return __uint_as_float(((unsigned int)v) << 16);
}
__device__ __forceinline__ unsigned short f2bf(float f) {
    unsigned int u = __float_as_uint(f);
    u += 0x7FFFu + ((u >> 16) & 1u);   // round-to-nearest-even
    return (unsigned short)(u >> 16);
}

// nontemporal loads ONLY for pure streams with zero reuse (ei scans)
__device__ __forceinline__ int ntl(const int* p) { return __builtin_nontemporal_load(p); }
__device__ __forceinline__ int4v ntl4(const int4v* p) { return __builtin_nontemporal_load(p); }

// ---------------- CSR build ----------------
// XCD-sharded, int4-batched dst scan.
__global__ __launch_bounds__(256) void count_kernel(const int* __restrict__ dst,
                                                    int* __restrict__ cnt) {
    const int xcd = blockIdx.x & (NXCD - 1);
    const int lo = xcd * (NN / NXCD);
    const int hi = (xcd == NXCD - 1) ? NN : lo + (NN / NXCD);
    const int slot = blockIdx.x >> 3;
    const int nslot = gridDim.x >> 3;
    const int4v* d4 = (const int4v*)dst;
    for (int e = slot * blockDim.x + threadIdx.x; e < NE / 4; e += nslot * blockDim.x) {
        int4v d = ntl4(d4 + e);
#pragma unroll
        for (int k = 0; k < 4; ++k) {
            int dd = d[k];
            if (dd >= lo && dd < hi) atomicAdd(&cnt[dd], 1);
        }
    }
}

__global__ __launch_bounds__(256) void dis_kernel(const int* __restrict__ cnt,
                                                  float* __restrict__ dis) {
    for (int i = blockIdx.x * blockDim.x + threadIdx.x; i < NN; i += gridDim.x * blockDim.x)
        dis[i] = rsqrtf((float)(cnt[i] + 1));   // +1 self loop
}

__global__ __launch_bounds__(256) void scan_partial(const int* __restrict__ cnt,
                                                    int* __restrict__ bsum) {
    __shared__ int ls[256];
    const int tid = threadIdx.x;
    int base = blockIdx.x * SCAN_CHUNK + tid * 8;
    int s = 0;
#pragma unroll
    for (int k = 0; k < 8; ++k) {
        int idx = base + k;
        s += (idx < NN) ? cnt[idx] : 0;
    }
    ls[tid] = s;
    __syncthreads();
    for (int off = 128; off > 0; off >>= 1) {
        if (tid < off) ls[tid] += ls[tid + off];
        __syncthreads();
    }
    if (tid == 0) bsum[blockIdx.x] = ls[0];
}

__global__ __launch_bounds__(64) void scan_bsum(int* __restrict__ bsum, int* __restrict__ off) {
    if (threadIdx.x == 0) {
        int run = 0;
        for (int i = 0; i < SCAN_NBLK; ++i) {
            int t = bsum[i];
            bsum[i] = run;
            run += t;
        }
        off[NN] = NE;
    }
}

__global__ __launch_bounds__(256) void scan_scatter(const int* __restrict__ cnt,
                                                    const int* __restrict__ bsum,
                                                    int* __restrict__ off,
                                                    int* __restrict__ cur) {
    __shared__ int part[256];
    const int tid = threadIdx.x;
    const int base = blockIdx.x * SCAN_CHUNK + tid * 8;
    int v[8];
    int s = 0;
#pragma unroll
    for (int k = 0; k < 8; ++k) {
        int idx = base + k;
        v[k] = (idx < NN) ? cnt[idx] : 0;
        s += v[k];
    }
    part[tid] = s;
    __syncthreads();
    if (tid == 0) {
        int run = 0;
        for (int i = 0; i < 256; ++i) {
            int t = part[i];
            part[i] = run;
            run += t;
        }
    }
    __syncthreads();
    int run = bsum[blockIdx.x] + part[tid];
#pragma unroll
    for (int k = 0; k < 8; ++k) {
        int idx = base + k;
        if (idx < NN) { off[idx] = run; cur[idx] = run; }
        run += v[k];
    }
}

// XCD-sharded fill; int4-batched dst scan, nt store of esrc.
__global__ __launch_bounds__(256) void fill_kernel(const int* __restrict__ ei,
                                                   int* __restrict__ cur,
                                                   int* __restrict__ esrc) {
    const int xcd = blockIdx.x & (NXCD - 1);
    const int lo = xcd * (NN / NXCD);
    const int hi = (xcd == NXCD - 1) ? NN : lo + (NN / NXCD);
    const int slot = blockIdx.x >> 3;
    const int nslot = gridDim.x >> 3;
    const int4v* d4 = (const int4v*)(ei + NE);
    for (int e4 = slot * blockDim.x + threadIdx.x; e4 < NE / 4; e4 += nslot * blockDim.x) {
        int4v d = ntl4(d4 + e4);
#pragma unroll
        for (int k = 0; k < 4; ++k) {
            int dd = d[k];
            if (dd >= lo && dd < hi) {
                int pos = atomicAdd(&cur[dd], 1);
                int s = ntl(ei + 4 * e4 + k);
                __builtin_nontemporal_store(s, &esrc[pos]);
            }
        }
    }
}

// ---------------- dense GEMM: h2[N,64] = bf16( (bn?(x)[N,K] @ W[K,64]) * dis[row] )
template <int K, int TR, bool BN>
__global__ __launch_bounds__(256) void gemm_lds(const float* __restrict__ x,
                                                const float* __restrict__ W,
                                                const float* __restrict__ dis,
                                                const float* __restrict__ sc,
                                                const float* __restrict__ sh,
                                                unsigned short* __restrict__ h2) {
    __shared__ float xs[TR][K];
    const int tid = threadIdx.x;
    const int lane = tid & 63;
    const int wv = tid >> 6;
    float w[K];
#pragma unroll
    for (int k = 0; k < K; ++k) w[k] = W[k * 64 + lane];

    float4 scv, shv;
    if (BN) {
        const int c4 = tid & (K / 4 - 1);   // column group is constant per thread
        scv = ((const float4*)sc)[c4];
        shv = ((const float4*)sh)[c4];
    }

    const int row0 = blockIdx.x * TR;
    const int remRows = NN - row0;
    const int nvec = ((remRows >= TR) ? TR : remRows) * K / 4;
    const float4* srcv = (const float4*)(x + (long long)row0 * K);
    float4* dstv = (float4*)&xs[0][0];
    for (int i = tid; i < nvec; i += 256) {
        float4 v = srcv[i];
        if (BN) {
            v.x = fmaxf(fmaf(v.x, scv.x, shv.x), 0.f);
            v.y = fmaxf(fmaf(v.y, scv.y, shv.y), 0.f);
            v.z = fmaxf(fmaf(v.z, scv.z, shv.z), 0.f);
            v.w = fmaxf(fmaf(v.w, scv.w, shv.w), 0.f);
        }
        dstv[i] = v;
    }
    __syncthreads();

    const int rpw = TR / 4;
#pragma unroll
    for (int rr = 0; rr < rpw; ++rr) {
        const int r = wv * rpw + rr;
        const int row = row0 + r;
        if (row >= NN) break;
        float a0 = 0.f, a1 = 0.f, a2 = 0.f, a3 = 0.f;
#pragma unroll
        for (int k = 0; k < K; k += 4) {
            float4 xv = *(const float4*)&xs[r][k];
            a0 = fmaf(xv.x, w[k + 0], a0);
            a1 = fmaf(xv.y, w[k + 1], a1);
            a2 = fmaf(xv.z, w[k + 2], a2);
            a3 = fmaf(xv.w, w[k + 3], a3);
        }
        h2[row * 64 + lane] = f2bf(((a0 + a1) + (a2 + a3)) * dis[row]);
    }
}

// ---------------- CSR gather, half-wave: 2 nodes/wave, 32 lanes/node --------
// Each lane owns a channel PAIR (ushort2 = 4B). One dependence chain per
// lane; tail handled branch-free: unconditional index load + cndmask to a
// zeroed pad row NN (L2-hot). jb/deg differ per half-wave; loop bound is the
// wave-max so loads stay unpredicated.
__global__ __launch_bounds__(256) void agg_csr(const int* __restrict__ off,
                                               const int* __restrict__ esrc,
                                               const float* __restrict__ dis,
                                               const unsigned short* __restrict__ h2,
                                               float* __restrict__ y) {
    const int tid = threadIdx.x;
    const int wv = tid >> 6;
    const int lane = tid & 63;
    const int half = lane >> 5;
    const int c = lane & 31;                 // channel-pair index
    const int node = blockIdx.x * 8 + wv * 2 + half;
    const ushort2* h2v = (const ushort2*)h2; // row stride = 32 pairs
    ushort2 p0 = h2v[node * 32 + c];
    float ax = bf2f(p0.x), ay = bf2f(p0.y);
    const int jb = off[node];
    const int deg = off[node + 1] - jb;
    const int m = max(deg, __shfl_xor(deg, 32));
#pragma unroll 8
    for (int t = 0; t < m; ++t) {
        int sv = esrc[jb + t];               // safe: esrc has valid slack after it
        int s = (t < deg) ? sv : NN;         // pad row NN is zeroed
        ushort2 p = h2v[s * 32 + c];
        ax += bf2f(p.x);
        ay += bf2f(p.y);
    }
    float dn = dis[node];
    ((float2*)(y + node * 64))[c] = make_float2(ax * dn, ay * dn);
}

// ---------------- layer-3 agg (half-wave) fused with JK max + final --------
__global__ __launch_bounds__(256) void agg_final(const int* __restrict__ off,
                                                 const int* __restrict__ esrc,
                                                 const float* __restrict__ dis,
                                                 const unsigned short* __restrict__ h2,
                                                 const float* __restrict__ x1,
                                                 const float* __restrict__ x2,
                                                 const float* __restrict__ sc1,
                                                 const float* __restrict__ sh1,
                                                 const float* __restrict__ sc2,
                                                 const float* __restrict__ sh2,
                                                 const float* __restrict__ b3,
                                                 const float* __restrict__ Wf,
                                                 const float* __restrict__ bf,
                                                 float* __restrict__ out) {
    __shared__ float m[8][64];
    const int tid = threadIdx.x;
    const int wv = tid >> 6;
    const int lane = tid & 63;
    const int half = lane >> 5;
    const int c = lane & 31;
    const int node = blockIdx.x * 8 + wv * 2 + half;
    const ushort2* h2v = (const ushort2*)h2;
    ushort2 p0 = h2v[node * 32 + c];
    float ax = bf2f(p0.x), ay = bf2f(p0.y);
    const int jb = off[node];
    const int deg = off[node + 1] - jb;
    const int mm = max(deg, __shfl_xor(deg, 32));
#pragma unroll 8
    for (int t = 0; t < mm; ++t) {
        int sv = esrc[jb + t];
        int s = (t < deg) ? sv : NN;
        ushort2 p = h2v[s * 32 + c];
        ax += bf2f(p.x);
        ay += bf2f(p.y);
    }
    const float dn = dis[node];
    const int c0 = 2 * c;
    const int o = node * 64 + c0;
    float2 x1v = *(const float2*)(x1 + o);
    float2 x2v = *(const float2*)(x2 + o);
    float v3x = fmaf(ax, dn, b3[c0]);
    float v3y = fmaf(ay, dn, b3[c0 + 1]);
    float v1x = fmaxf(fmaf(x1v.x, sc1[c0], sh1[c0]), 0.f);
    float v1y = fmaxf(fmaf(x1v.y, sc1[c0 + 1], sh1[c0 + 1]), 0.f);
    float v2x = fmaxf(fmaf(x2v.x, sc2[c0], sh2[c0]), 0.f);
    float v2y = fmaxf(fmaf(x2v.y, sc2[c0 + 1], sh2[c0 + 1]), 0.f);
    const int rl = wv * 2 + half;
    m[rl][c0] = fmaxf(fmaxf(v1x, v2x), v3x);
    m[rl][c0 + 1] = fmaxf(fmaxf(v1y, v2y), v3y);
    __syncthreads();
#pragma unroll
    for (int rr = wv; rr < 8; rr += 4) {
        if (lane < DOUT) {
            float a2 = bf[lane];
#pragma unroll
            for (int k = 0; k < 64; ++k) a2 += m[rr][k] * Wf[k * DOUT + lane];
            out[(blockIdx.x * 8 + rr) * DOUT + lane] = a2;
        }
    }
}

// ---------------- per-channel sum / sumsq ----------------
__global__ __launch_bounds__(256) void stats_kernel(const float* __restrict__ y, float* stats) {
    const int tid = threadIdx.x;
    const int c = tid & 63, rg = tid >> 6;
    float s = 0.f, s2 = 0.f;
    for (int row = blockIdx.x * 4 + rg; row < NN; row += gridDim.x * 4) {
        float v = y[row * 64 + c];
        s += v;
        s2 += v * v;
    }
    __shared__ float ls[256], ls2[256];
    ls[tid] = s; ls2[tid] = s2;
    __syncthreads();
    if (tid < 64) {
        s = ls[tid] + ls[tid + 64] + ls[tid + 128] + ls[tid + 192];
        s2 = ls2[tid] + ls2[tid + 64] + ls2[tid + 128] + ls2[tid + 192];
        atomicAdd(&stats[tid], s);
        atomicAdd(&stats[64 + tid], s2);
    }
}

// ---------------- BN coefficients ----------------
__global__ __launch_bounds__(64) void bn_coef(const float* __restrict__ stats,
                                              const float* __restrict__ g,
                                              const float* __restrict__ beta,
                                              float* __restrict__ sc,
                                              float* __restrict__ sh) {
    const int c = threadIdx.x;
    const float invN = 1.0f / NN;
    float m = stats[c] * invN;
    float var = stats[64 + c] * invN - m * m;
    float s = g[c] * rsqrtf(var + EPS);
    sc[c] = s;
    sh[c] = beta[c] - m * s;
}

extern "C" void kernel_launch(void* const* d_in, const int* in_sizes, int n_in,
                              void* d_out, int out_size, void* d_ws, size_t ws_size,
                              hipStream_t stream) {
    const float* node_feat = (const float*)d_in[0];
    const int*   ei        = (const int*)d_in[1];
    const float* W1 = (const float*)d_in[2];
    const float* g1 = (const float*)d_in[4];
    const float* beta1 = (const float*)d_in[5];
    const float* W2 = (const float*)d_in[6];
    const float* g2 = (const float*)d_in[8];
    const float* beta2 = (const float*)d_in[9];
    const float* W3 = (const float*)d_in[10];
    const float* b3 = (const float*)d_in[11];
    const float* Wf = (const float*)d_in[12];
    const float* bf = (const float*)d_in[13];
    float* out = (float*)d_out;

    // workspace layout (esrc followed by cnt so tail over-reads stay in-bounds)
    float* ws  = (float*)d_ws;
    float* dis = ws;                                       // N
    unsigned short* h2 = (unsigned short*)(dis + NN);      // (N+1)*64 bf16 (+pad row)
    float* x1  = (float*)(h2 + (NN + 1) * 64);             // N*64 f32
    float* x2  = x1 + NN * 64;
    float* stats = x2 + NN * 64;                           // 128
    float* sc1 = stats + 128;                              // 64
    float* sh1 = sc1 + 64;                                 // 64
    float* sc2 = sh1 + 64;                                 // 64
    float* sh2 = sc2 + 64;                                 // 64
    int* esrc = (int*)(sh2 + 64);                          // E
    int* cnt  = esrc + NE;                                 // N  (also esrc slack)
    int* cur  = cnt + NN;                                  // N
    int* bsum = cur + NN;                                  // 64
    int* off  = bsum + 64;                                 // N+1

    const int B = 256;
    const int gElem = 2048;
    const int gAgg = NN / 8;      // 12500 (8 nodes per block)

    // ---- CSR build + normalization ----
    hipMemsetAsync(cnt, 0, NN * sizeof(int), stream);
    hipMemsetAsync(h2 + NN * 64, 0, 64 * sizeof(unsigned short), stream);  // pad row
    count_kernel<<<gElem, B, 0, stream>>>(ei + NE, cnt);
    dis_kernel<<<512, B, 0, stream>>>(cnt, dis);
    scan_partial<<<SCAN_NBLK, B, 0, stream>>>(cnt, bsum);
    scan_bsum<<<1, 64, 0, stream>>>(bsum, off);
    scan_scatter<<<SCAN_NBLK, B, 0, stream>>>(cnt, bsum, off, cur);
    fill_kernel<<<gElem, B, 0, stream>>>(ei, cur, esrc);

    // ---- layer 1 ----
    gemm_lds<DIN, 32, false><<<(NN + 31) / 32, B, 0, stream>>>(node_feat, W1, dis, nullptr, nullptr, h2);
    agg_csr<<<gAgg, B, 0, stream>>>(off, esrc, dis, h2, x1);
    hipMemsetAsync(stats, 0, 128 * sizeof(float), stream);
    stats_kernel<<<512, B, 0, stream>>>(x1, stats);
    bn_coef<<<1, 64, 0, stream>>>(stats, g1, beta1, sc1, sh1);

    // ---- layer 2 (BN1+ReLU fused into staging) ----
    gemm_lds<HDIM, 64, true><<<(NN + 63) / 64, B, 0, stream>>>(x1, W2, dis, sc1, sh1, h2);
    agg_csr<<<gAgg, B, 0, stream>>>(off, esrc, dis, h2, x2);
    hipMemsetAsync(stats, 0, 128 * sizeof(float), stream);
    stats_kernel<<<512, B, 0, stream>>>(x2, stats);
    bn_coef<<<1, 64, 0, stream>>>(stats, g2, beta2, sc2, sh2);

    // ---- layer 3 (BN2+ReLU fused into staging; agg fused with JK+final) ----
    gemm_lds<HDIM, 64, true><<<(NN + 63) / 64, B, 0, stream>>>(x2, W3, dis, sc2, sh2, h2);
    agg_final<<<gAgg, B, 0, stream>>>(off, esrc, dis, h2, x1, x2,
                                      sc1, sh1, sc2, sh2, b3, Wf, bf, out);
}